// Round 2
// baseline (96617.090 us; speedup 1.0000x reference)
//
#include <hip/hip_runtime.h>
#include <hip/hip_bf16.h>
#include <cstddef>

// GRU  B=32, L=1024, D_IN=512, H=512
// Strategy R2: persistent cooperative recurrence with register-resident weights.
//  - 256 WGs = 32 batches x 8 column-slices. WG (b,j) owns 64 r-cols, 64 z-cols,
//    64 cand-cols (rows j*64..j*64+63 of each gate block) with all 512 k.
//  - Weights loaded ONCE per launch into VGPRs (192 floats/thread).
//  - Per step: phase A (r,z matvec, 8 waves x 128-k slices) -> publish rh slice;
//    phase B (cand matvec, 8 waves x 64-k slices) -> publish h slice.
//  - Cross-WG sync: per-batch monotonic counters, agent-scope acquire/release.
//    Block swizzle b=blk&31 puts a batch's 8 WGs on one XCD (round-robin dispatch).

#define Bsz   32
#define Lsz   1024
#define Hsz   512
#define NG    1536

__device__ __forceinline__ float sigmoidf_(float v) {
    return 1.0f / (1.0f + __expf(-v));
}
__device__ __forceinline__ float tanhf_(float v) {
    float e = __expf(2.0f * v);
    return 1.0f - 2.0f / (e + 1.0f);
}

__device__ __forceinline__ void wait_ge(int* cnt, int target) {
    while (__hip_atomic_load(cnt, __ATOMIC_ACQUIRE, __HIP_MEMORY_SCOPE_AGENT) < target)
        __builtin_amdgcn_s_sleep(2);
}

// ---------------- transpose weights to k-major -----------------------------
__global__ __launch_bounds__(256) void transpose_k(const float* __restrict__ src,
                                                   float* __restrict__ dst,
                                                   int G, int K, int S) {
    __shared__ float tile[32][33];
    int g0 = blockIdx.x * 32, k0 = blockIdx.y * 32;
    int lx = threadIdx.x & 31, ly = threadIdx.x >> 5;
    #pragma unroll
    for (int i = ly; i < 32; i += 8)
        tile[i][lx] = src[(size_t)(g0 + i) * S + (k0 + lx)];
    __syncthreads();
    #pragma unroll
    for (int i = ly; i < 32; i += 8)
        dst[(size_t)(k0 + i) * G + (g0 + lx)] = tile[lx][i];
}

__global__ __launch_bounds__(256) void init_h(const float* __restrict__ h0,
                                              float* __restrict__ h_buf) {
    int i = blockIdx.x * 256 + threadIdx.x;
    h_buf[i] = h0[i];
}

__global__ __launch_bounds__(64) void zero_counters(int* __restrict__ h_cnt,
                                                    int* __restrict__ rh_cnt) {
    int i = threadIdx.x;
    if (i < 32) { h_cnt[i] = 0; rh_cnt[i] = 0; }
}

// ---------------- input-projection GEMM (unchanged, verified R1) ------------
__global__ __launch_bounds__(256) void gemm_pre(const float* __restrict__ x,
                                                const float* __restrict__ W_ru,
                                                const float* __restrict__ b_ru,
                                                const float* __restrict__ W_c,
                                                const float* __restrict__ b_c,
                                                float* __restrict__ pre,
                                                int t0) {
    __shared__ float As[8][128];
    __shared__ float Bs[8][128];
    const int tid = threadIdx.x;
    const int bm = blockIdx.x, bn = blockIdx.y;
    const int tx = tid & 15, ty = tid >> 4;

    const int lrow = tid >> 1;
    const int lk4  = (tid & 1) * 4;
    const int grow = bm * 128 + lrow;
    const int tt = grow >> 5, bb = grow & 31;
    const float* xrow = x + ((size_t)bb * Lsz + (t0 + tt)) * 512;
    const int gn = bn * 128 + lrow;
    const float* wrow = (gn < 1024) ? (W_ru + (size_t)gn * 1024 + 512)
                                    : (W_c  + (size_t)(gn - 1024) * 1024 + 512);

    float acc[8][8];
    #pragma unroll
    for (int i = 0; i < 8; ++i)
        #pragma unroll
        for (int j = 0; j < 8; ++j) acc[i][j] = 0.0f;

    for (int k0 = 0; k0 < 512; k0 += 8) {
        float4 av = *(const float4*)(xrow + k0 + lk4);
        float4 bv = *(const float4*)(wrow + k0 + lk4);
        __syncthreads();
        As[lk4 + 0][lrow] = av.x; As[lk4 + 1][lrow] = av.y;
        As[lk4 + 2][lrow] = av.z; As[lk4 + 3][lrow] = av.w;
        Bs[lk4 + 0][lrow] = bv.x; Bs[lk4 + 1][lrow] = bv.y;
        Bs[lk4 + 2][lrow] = bv.z; Bs[lk4 + 3][lrow] = bv.w;
        __syncthreads();
        #pragma unroll
        for (int k = 0; k < 8; ++k) {
            float a[8], b[8];
            *(float4*)&a[0] = *(const float4*)&As[k][ty * 8];
            *(float4*)&a[4] = *(const float4*)&As[k][ty * 8 + 4];
            *(float4*)&b[0] = *(const float4*)&Bs[k][tx * 8];
            *(float4*)&b[4] = *(const float4*)&Bs[k][tx * 8 + 4];
            #pragma unroll
            for (int i = 0; i < 8; ++i)
                #pragma unroll
                for (int j = 0; j < 8; ++j)
                    acc[i][j] += a[i] * b[j];
        }
    }

    const int row0 = bm * 128 + ty * 8;
    const int col0 = bn * 128 + tx * 8;
    float bias[8];
    #pragma unroll
    for (int j = 0; j < 8; ++j) {
        int c = col0 + j;
        bias[j] = (c < 1024) ? b_ru[c] : b_c[c - 1024];
    }
    #pragma unroll
    for (int i = 0; i < 8; ++i) {
        float4 v0 = make_float4(acc[i][0] + bias[0], acc[i][1] + bias[1],
                                acc[i][2] + bias[2], acc[i][3] + bias[3]);
        float4 v1 = make_float4(acc[i][4] + bias[4], acc[i][5] + bias[5],
                                acc[i][6] + bias[6], acc[i][7] + bias[7]);
        float* p = pre + (size_t)(row0 + i) * NG + col0;
        *(float4*)p = v0;
        *(float4*)(p + 4) = v1;
    }
}

// ---------------- persistent recurrence ------------------------------------
__global__ __launch_bounds__(512, 2)
void gru_persist(const float* __restrict__ WtR,   // [k][1024] k-major Wh_ru
                 const float* __restrict__ WtC,   // [k][512]  k-major Wh_c
                 const float* __restrict__ pre,   // [Tc][32][1536]
                 float* __restrict__ h_buf,       // [32][512]
                 float* __restrict__ rh_buf,      // [32][512]
                 int* __restrict__ h_cnt,         // [32]
                 int* __restrict__ rh_cnt,        // [32]
                 float* __restrict__ out,
                 float* __restrict__ hlast,
                 int t0, int Tc) {
    const int blk  = blockIdx.x;
    const int b    = blk & 31;   // batch (fast-varying -> same XCD for a batch)
    const int j    = blk >> 5;   // column slice 0..7
    const int tid  = threadIdx.x;
    const int wave = tid >> 6;   // 0..7
    const int lane = tid & 63;
    const int g    = wave >> 2;  // phase A: 0=r, 1=z
    const int ks   = wave & 3;   // phase A: k-slice of 128

    __shared__ float h_s[512];
    __shared__ float rh_s[512];
    __shared__ float z_s[64];
    __shared__ float pA[8][64];
    __shared__ float pB[8][64];

    // ---- load resident weights into registers (once per launch) ----
    float wA[128];
    {
        const float* baseA = WtR + (size_t)(ks * 128) * 1024 + (g * 512 + j * 64 + lane);
        #pragma unroll
        for (int k = 0; k < 128; ++k) wA[k] = baseA[(size_t)k * 1024];
    }
    float wB[64];
    {
        const float* baseB = WtC + (size_t)(wave * 64) * 512 + (j * 64 + lane);
        #pragma unroll
        for (int k = 0; k < 64; ++k) wB[k] = baseB[(size_t)k * 512];
    }

    for (int s = 0; s < Tc; ++s) {
        const int tg = t0 + s;
        const float* prow = pre + ((size_t)s * Bsz + b) * NG;

        // prefetch this step's pre slice (independent of h -> overlaps spin)
        float my_pre = 0.0f;
        if (tid < 192) {
            int grp = tid >> 6;             // 0=r, 1=z, 2=c
            int c   = tid & 63;
            my_pre = prow[grp * 512 + j * 64 + c];
        }

        // wait until all slices published h for step s-1
        if (s > 0) wait_ge(h_cnt + b, 8 * s);

        // stage h into LDS
        h_s[tid] = h_buf[b * 512 + tid];
        __syncthreads();

        // ---- phase A: r,z matvec. wave (g,ks): 64 cols x 128 k ----
        {
            float acc = 0.0f;
            #pragma unroll
            for (int k4 = 0; k4 < 32; ++k4) {
                float4 h4 = *(const float4*)&h_s[ks * 128 + 4 * k4];
                acc += wA[4 * k4 + 0] * h4.x + wA[4 * k4 + 1] * h4.y
                     + wA[4 * k4 + 2] * h4.z + wA[4 * k4 + 3] * h4.w;
            }
            pA[wave][lane] = acc;
        }
        __syncthreads();

        // finalize r,z; publish rh slice
        if (tid < 128) {
            int grp = tid >> 6;   // 0=r, 1=z  (matches my_pre mapping)
            int c   = tid & 63;
            float v = pA[grp * 4 + 0][c] + pA[grp * 4 + 1][c]
                    + pA[grp * 4 + 2][c] + pA[grp * 4 + 3][c] + my_pre;
            float gate = sigmoidf_(v);
            if (grp == 0) {
                rh_buf[b * 512 + j * 64 + c] = gate * h_s[j * 64 + c];
            } else {
                z_s[c] = gate;
            }
        }
        __syncthreads();   // drains stores (vmcnt(0)) before release
        if (tid == 0)
            __hip_atomic_fetch_add(rh_cnt + b, 1, __ATOMIC_RELEASE, __HIP_MEMORY_SCOPE_AGENT);

        wait_ge(rh_cnt + b, 8 * (s + 1));

        // stage rh into LDS
        rh_s[tid] = rh_buf[b * 512 + tid];
        __syncthreads();

        // ---- phase B: cand matvec. wave: 64 cols x 64 k ----
        {
            float acc = 0.0f;
            #pragma unroll
            for (int k4 = 0; k4 < 16; ++k4) {
                float4 r4 = *(const float4*)&rh_s[wave * 64 + 4 * k4];
                acc += wB[4 * k4 + 0] * r4.x + wB[4 * k4 + 1] * r4.y
                     + wB[4 * k4 + 2] * r4.z + wB[4 * k4 + 3] * r4.w;
            }
            pB[wave][lane] = acc;
        }
        __syncthreads();

        // finalize cand + h update (threads 128..191 hold my_pre for cand)
        if (tid >= 128 && tid < 192) {
            int c = tid - 128;
            float v = pB[0][c] + pB[1][c] + pB[2][c] + pB[3][c]
                    + pB[4][c] + pB[5][c] + pB[6][c] + pB[7][c] + my_pre;
            float cand = tanhf_(v);
            float z  = z_s[c];
            float hp = h_s[j * 64 + c];
            float hn = (1.0f - z) * hp + z * cand;
            h_buf[b * 512 + j * 64 + c] = hn;
            out[((size_t)b * Lsz + tg) * Hsz + j * 64 + c] = hn;
            if (tg == Lsz - 1) hlast[b * Hsz + j * 64 + c] = hn;
        }
        __syncthreads();   // drains stores before release
        if (tid == 0)
            __hip_atomic_fetch_add(h_cnt + b, 1, __ATOMIC_RELEASE, __HIP_MEMORY_SCOPE_AGENT);
    }
}

// ---------------------------------------------------------------------------
extern "C" void kernel_launch(void* const* d_in, const int* in_sizes, int n_in,
                              void* d_out, int out_size, void* d_ws, size_t ws_size,
                              hipStream_t stream) {
    const float* x     = (const float*)d_in[0];
    const float* h0    = (const float*)d_in[1];
    const float* W_ru  = (const float*)d_in[2];
    const float* b_ru  = (const float*)d_in[3];
    const float* W_c   = (const float*)d_in[4];
    const float* b_c   = (const float*)d_in[5];
    float* out   = (float*)d_out;
    float* hlast = out + (size_t)Bsz * Lsz * Hsz;

    float* ws     = (float*)d_ws;
    float* WtR    = ws;                          // 512*1024
    float* WtC    = WtR + 512 * 1024;            // 512*512
    float* h_buf  = WtC + 512 * 512;             // 32*512
    float* rh_buf = h_buf + Bsz * Hsz;           // 32*512
    int*   h_cnt  = (int*)(rh_buf + Bsz * Hsz);  // 32
    int*   rh_cnt = h_cnt + 32;                  // 32
    float* pre    = (float*)(rh_cnt + 32);       // Tc*32*1536

    const size_t fixed_bytes = (size_t)((char*)pre - (char*)d_ws);
    int Tc = 256;
    while (Tc > 8 && fixed_bytes + (size_t)Tc * Bsz * NG * 4 > ws_size) Tc >>= 1;

    transpose_k<<<dim3(32, 16), 256, 0, stream>>>(W_ru, WtR, 1024, 512, 1024);
    transpose_k<<<dim3(16, 16), 256, 0, stream>>>(W_c,  WtC,  512, 512, 1024);
    init_h<<<(Bsz * Hsz) / 256, 256, 0, stream>>>(h0, h_buf);

    const int nchunks = Lsz / Tc;
    for (int cidx = 0; cidx < nchunks; ++cidx) {
        const int t0 = cidx * Tc;
        gemm_pre<<<dim3((Tc * Bsz) / 128, NG / 128), 256, 0, stream>>>(
            x, W_ru, b_ru, W_c, b_c, pre, t0);
        zero_counters<<<1, 64, 0, stream>>>(h_cnt, rh_cnt);

        void* args[] = { (void*)&WtR, (void*)&WtC, (void*)&pre,
                         (void*)&h_buf, (void*)&rh_buf,
                         (void*)&h_cnt, (void*)&rh_cnt,
                         (void*)&out, (void*)&hlast,
                         (void*)&t0, (void*)&Tc };
        hipLaunchCooperativeKernel((void*)gru_persist, dim3(256), dim3(512),
                                   args, 0, stream);
    }
}

// Round 6
// 91608.185 us; speedup vs baseline: 1.0547x; 1.0547x over previous
//
#include <hip/hip_runtime.h>
#include <hip/hip_bf16.h>
#include <cstddef>

// GRU  B=32, L=1024, D_IN=512, H=512
// R6 = R2's EXACT proven structure (256 WGs = 32 batches x 8 slices, 512 thr,
// every-thread ACQUIRE spin, tid-0 RELEASE fetch_add, per-chunk counters)
// with ONE change: weights bf16x2-packed, 96 u32/thread -> fits in VGPRs
// (R2's 192 fp32/thread didn't fit -> scratch spill -> 92 us/step).
// R3/R4/R5 failed because 512-WG cooperative launches exceeded coop capacity
// and the unchecked launch silently no-opped. Grid stays at 256 WGs.

#define Bsz   32
#define Lsz   1024
#define Hsz   512
#define NG    1536
#define NSL   8      // column slices per batch

__device__ __forceinline__ float sigmoidf_(float v) {
    return 1.0f / (1.0f + __expf(-v));
}
__device__ __forceinline__ float tanhf_(float v) {
    float e = __expf(2.0f * v);
    return 1.0f - 2.0f / (e + 1.0f);
}
__device__ __forceinline__ float bf_lo(unsigned u) { return __uint_as_float(u << 16); }
__device__ __forceinline__ float bf_hi(unsigned u) { return __uint_as_float(u & 0xffff0000u); }

__device__ __forceinline__ unsigned pack_bf16(float lo, float hi) {
    unsigned ulo = __float_as_uint(lo);
    unsigned uhi = __float_as_uint(hi);
    ulo = (ulo + 0x7fff + ((ulo >> 16) & 1)) >> 16;          // RNE
    uhi = (uhi + 0x7fff + ((uhi >> 16) & 1)) & 0xffff0000u;  // RNE
    return uhi | ulo;
}

// R2-proven: EVERY thread spins with agent-scope ACQUIRE.
__device__ __forceinline__ void wait_ge(int* cnt, int target) {
    int guard = 0;
    while (__hip_atomic_load(cnt, __ATOMIC_ACQUIRE, __HIP_MEMORY_SCOPE_AGENT) < target) {
        __builtin_amdgcn_s_sleep(2);
        if (++guard > (1 << 24)) break;   // fail visibly, never hang
    }
}

// ---------------- weight packing (one-time) --------------------------------
// WtRp[k2*1024 + g] = bf16x2( Wh_ru[g][2k2], Wh_ru[g][2k2+1] )
__global__ __launch_bounds__(256) void pack_wtr(const float* __restrict__ W_ru,
                                                unsigned* __restrict__ WtRp) {
    int idx = blockIdx.x * 256 + threadIdx.x;       // 256*1024
    int k2 = idx >> 10, g = idx & 1023;
    const float* p = W_ru + (size_t)g * 1024 + 2 * k2;
    WtRp[(size_t)k2 * 1024 + g] = pack_bf16(p[0], p[1]);
}
// WtCp[k2*512 + c] = bf16x2( Wh_c[c][2k2], Wh_c[c][2k2+1] )
__global__ __launch_bounds__(256) void pack_wtc(const float* __restrict__ W_c,
                                                unsigned* __restrict__ WtCp) {
    int idx = blockIdx.x * 256 + threadIdx.x;       // 256*512
    int k2 = idx >> 9, c = idx & 511;
    const float* p = W_c + (size_t)c * 1024 + 2 * k2;
    WtCp[(size_t)k2 * 512 + c] = pack_bf16(p[0], p[1]);
}

__global__ __launch_bounds__(256) void init_h(const float* __restrict__ h0,
                                              float* __restrict__ h_buf) {
    int i = blockIdx.x * 256 + threadIdx.x;
    h_buf[i] = h0[i];
}

__global__ __launch_bounds__(64) void zero_counters(int* __restrict__ h_cnt,
                                                    int* __restrict__ rh_cnt) {
    int i = threadIdx.x;
    if (i < 32) { h_cnt[i] = 0; rh_cnt[i] = 0; }
}

// ---------------- input-projection GEMM (verified R1) -----------------------
__global__ __launch_bounds__(256) void gemm_pre(const float* __restrict__ x,
                                                const float* __restrict__ W_ru,
                                                const float* __restrict__ b_ru,
                                                const float* __restrict__ W_c,
                                                const float* __restrict__ b_c,
                                                float* __restrict__ pre,
                                                int t0) {
    __shared__ float As[8][128];
    __shared__ float Bs[8][128];
    const int tid = threadIdx.x;
    const int bm = blockIdx.x, bn = blockIdx.y;
    const int tx = tid & 15, ty = tid >> 4;

    const int lrow = tid >> 1;
    const int lk4  = (tid & 1) * 4;
    const int grow = bm * 128 + lrow;
    const int tt = grow >> 5, bb = grow & 31;
    const float* xrow = x + ((size_t)bb * Lsz + (t0 + tt)) * 512;
    const int gn = bn * 128 + lrow;
    const float* wrow = (gn < 1024) ? (W_ru + (size_t)gn * 1024 + 512)
                                    : (W_c  + (size_t)(gn - 1024) * 1024 + 512);

    float acc[8][8];
    #pragma unroll
    for (int i = 0; i < 8; ++i)
        #pragma unroll
        for (int j = 0; j < 8; ++j) acc[i][j] = 0.0f;

    for (int k0 = 0; k0 < 512; k0 += 8) {
        float4 av = *(const float4*)(xrow + k0 + lk4);
        float4 bv = *(const float4*)(wrow + k0 + lk4);
        __syncthreads();
        As[lk4 + 0][lrow] = av.x; As[lk4 + 1][lrow] = av.y;
        As[lk4 + 2][lrow] = av.z; As[lk4 + 3][lrow] = av.w;
        Bs[lk4 + 0][lrow] = bv.x; Bs[lk4 + 1][lrow] = bv.y;
        Bs[lk4 + 2][lrow] = bv.z; Bs[lk4 + 3][lrow] = bv.w;
        __syncthreads();
        #pragma unroll
        for (int k = 0; k < 8; ++k) {
            float a[8], b[8];
            *(float4*)&a[0] = *(const float4*)&As[k][ty * 8];
            *(float4*)&a[4] = *(const float4*)&As[k][ty * 8 + 4];
            *(float4*)&b[0] = *(const float4*)&Bs[k][tx * 8];
            *(float4*)&b[4] = *(const float4*)&Bs[k][tx * 8 + 4];
            #pragma unroll
            for (int i = 0; i < 8; ++i)
                #pragma unroll
                for (int j = 0; j < 8; ++j)
                    acc[i][j] += a[i] * b[j];
        }
    }

    const int row0 = bm * 128 + ty * 8;
    const int col0 = bn * 128 + tx * 8;
    float bias[8];
    #pragma unroll
    for (int j = 0; j < 8; ++j) {
        int c = col0 + j;
        bias[j] = (c < 1024) ? b_ru[c] : b_c[c - 1024];
    }
    #pragma unroll
    for (int i = 0; i < 8; ++i) {
        float4 v0 = make_float4(acc[i][0] + bias[0], acc[i][1] + bias[1],
                                acc[i][2] + bias[2], acc[i][3] + bias[3]);
        float4 v1 = make_float4(acc[i][4] + bias[4], acc[i][5] + bias[5],
                                acc[i][6] + bias[6], acc[i][7] + bias[7]);
        float* p = pre + (size_t)(row0 + i) * NG + col0;
        *(float4*)p = v0;
        *(float4*)(p + 4) = v1;
    }
}

// ---------------- persistent recurrence (R2 structure) ----------------------
// WG (b = blk&31, j = blk>>5): owns cols [j*64, j*64+64) of r, z, cand.
// Phase A: 512 thr = 128 cols (64 r + 64 z) x 4 k-slices(128) -> 64 u32/thread.
// Phase B: 512 thr =  64 cols x 8 k-slices(64)                -> 32 u32/thread.
__global__ __launch_bounds__(512, 2)
void gru_persist(const unsigned* __restrict__ WtRp,  // [256][1024] bf16x2 k-major
                 const unsigned* __restrict__ WtCp,  // [256][512]
                 const float* __restrict__ pre,      // [Tc][32][1536]
                 float* __restrict__ h_buf,          // [32][512]
                 float* __restrict__ rh_buf,         // [32][512]
                 int* __restrict__ h_cnt,            // [32]
                 int* __restrict__ rh_cnt,           // [32]
                 float* __restrict__ out,
                 float* __restrict__ hlast,
                 int t0, int Tc) {
    const int tid = threadIdx.x;
    const int blk = blockIdx.x;
    const int b   = blk & 31;
    const int j   = blk >> 5;

    const int colA = tid & 127;         // 0..63 r-col, 64..127 z-col
    const int ksA  = tid >> 7;          // k-slice of 128 (64 bf16 pairs)
    const int colB = tid & 63;
    const int ksB  = tid >> 6;          // k-slice of 64 (32 bf16 pairs)

    __shared__ __align__(16) float h_s[512];
    __shared__ __align__(16) float rh_s[512];
    __shared__ float z_s[64];
    __shared__ float pA[4][128];
    __shared__ float pB[8][64];

    // ---- register-resident bf16x2 weights (96 u32/thread) ----
    unsigned wA2[64];
    {
        const int gA = (colA < 64) ? (j * 64 + colA) : (512 + j * 64 + (colA - 64));
        const unsigned* pa = WtRp + (size_t)(ksA * 64) * 1024 + gA;
        #pragma unroll 64
        for (int k2 = 0; k2 < 64; ++k2) wA2[k2] = pa[(size_t)k2 * 1024];
    }
    unsigned wB2[32];
    {
        const unsigned* pb = WtCp + (size_t)(ksB * 32) * 512 + (j * 64 + colB);
        #pragma unroll 32
        for (int k2 = 0; k2 < 32; ++k2) wB2[k2] = pb[(size_t)k2 * 512];
    }

    int* hC  = h_cnt  + b;
    int* rhC = rh_cnt + b;

    for (int s = 0; s < Tc; ++s) {
        const int tg = t0 + s;
        const float* prow = pre + ((size_t)s * Bsz + b) * NG;

        // prefetch pre (independent of h -> overlaps the wait)
        float preA = 0.0f, preC = 0.0f;
        if (tid < 128)
            preA = prow[(tid < 64) ? (j * 64 + tid) : (512 + j * 64 + (tid - 64))];
        if (tid < 64)
            preC = prow[1024 + j * 64 + tid];

        // wait for all 8 slices of previous step (counters zeroed per chunk)
        if (s > 0) wait_ge(hC, NSL * s);

        h_s[tid] = h_buf[b * 512 + tid];
        __syncthreads();

        // ---- phase A: r,z partials (128 k per slice) ----
        {
            float acc = 0.0f;
            const float* hp = &h_s[ksA * 128];
            #pragma unroll 64
            for (int k2 = 0; k2 < 64; ++k2) {
                unsigned u = wA2[k2];
                acc += bf_lo(u) * hp[2 * k2] + bf_hi(u) * hp[2 * k2 + 1];
            }
            pA[ksA][colA] = acc;
        }
        __syncthreads();

        if (tid < 128) {
            float v = pA[0][tid] + pA[1][tid] + pA[2][tid] + pA[3][tid] + preA;
            float gate = sigmoidf_(v);
            if (tid < 64) {
                rh_buf[b * 512 + j * 64 + tid] = gate * h_s[j * 64 + tid];
            } else {
                z_s[tid - 64] = gate;
            }
        }
        __syncthreads();   // vmcnt(0) drain in every wave before release
        if (tid == 0)
            __hip_atomic_fetch_add(rhC, 1, __ATOMIC_RELEASE, __HIP_MEMORY_SCOPE_AGENT);

        wait_ge(rhC, NSL * (s + 1));

        rh_s[tid] = rh_buf[b * 512 + tid];
        __syncthreads();

        // ---- phase B: cand partials (64 k per slice) ----
        {
            float acc = 0.0f;
            const float* rp = &rh_s[ksB * 64];
            #pragma unroll 32
            for (int k2 = 0; k2 < 32; ++k2) {
                unsigned u = wB2[k2];
                acc += bf_lo(u) * rp[2 * k2] + bf_hi(u) * rp[2 * k2 + 1];
            }
            pB[ksB][colB] = acc;
        }
        __syncthreads();

        if (tid < 64) {
            float v = preC;
            #pragma unroll
            for (int i = 0; i < 8; ++i) v += pB[i][tid];
            float cand = tanhf_(v);
            float z  = z_s[tid];
            float hp = h_s[j * 64 + tid];
            float hn = (1.0f - z) * hp + z * cand;
            h_buf[b * 512 + j * 64 + tid] = hn;
            out[((size_t)b * Lsz + tg) * Hsz + j * 64 + tid] = hn;
            if (tg == Lsz - 1) hlast[b * Hsz + j * 64 + tid] = hn;
        }
        __syncthreads();   // drain before release
        if (tid == 0)
            __hip_atomic_fetch_add(hC, 1, __ATOMIC_RELEASE, __HIP_MEMORY_SCOPE_AGENT);
    }
}

// ---------------------------------------------------------------------------
extern "C" void kernel_launch(void* const* d_in, const int* in_sizes, int n_in,
                              void* d_out, int out_size, void* d_ws, size_t ws_size,
                              hipStream_t stream) {
    const float* x     = (const float*)d_in[0];
    const float* h0    = (const float*)d_in[1];
    const float* W_ru  = (const float*)d_in[2];
    const float* b_ru  = (const float*)d_in[3];
    const float* W_c   = (const float*)d_in[4];
    const float* b_c   = (const float*)d_in[5];
    float* out   = (float*)d_out;
    float* hlast = out + (size_t)Bsz * Lsz * Hsz;

    char* wsb      = (char*)d_ws;
    unsigned* WtRp = (unsigned*)wsb;                       // 256*1024 u32
    unsigned* WtCp = WtRp + 256 * 1024;                    // 256*512 u32
    float* h_buf   = (float*)(WtCp + 256 * 512);           // 32*512
    float* rh_buf  = h_buf + Bsz * Hsz;                    // 32*512
    int*   h_cnt   = (int*)(rh_buf + Bsz * Hsz);           // 32
    int*   rh_cnt  = h_cnt + 32;                           // 32
    float* pre     = (float*)(rh_cnt + 32);                // Tc*32*1536

    const size_t fixed_bytes = (size_t)((char*)pre - (char*)d_ws);
    int Tc = 256;
    while (Tc > 8 && fixed_bytes + (size_t)Tc * Bsz * NG * 4 > ws_size) Tc >>= 1;

    pack_wtr<<<(256 * 1024) / 256, 256, 0, stream>>>(W_ru, WtRp);
    pack_wtc<<<(256 * 512) / 256, 256, 0, stream>>>(W_c, WtCp);
    init_h<<<(Bsz * Hsz) / 256, 256, 0, stream>>>(h0, h_buf);

    const int nchunks = Lsz / Tc;
    for (int cidx = 0; cidx < nchunks; ++cidx) {
        int t0 = cidx * Tc;
        gemm_pre<<<dim3((Tc * Bsz) / 128, NG / 128), 256, 0, stream>>>(
            x, W_ru, b_ru, W_c, b_c, pre, t0);
        zero_counters<<<1, 64, 0, stream>>>(h_cnt, rh_cnt);

        void* args[] = { (void*)&WtRp, (void*)&WtCp, (void*)&pre,
                         (void*)&h_buf, (void*)&rh_buf,
                         (void*)&h_cnt, (void*)&rh_cnt,
                         (void*)&out, (void*)&hlast,
                         (void*)&t0, (void*)&Tc };
        hipError_t e = hipLaunchCooperativeKernel((void*)gru_persist,
                                                  dim3(Bsz * NSL), dim3(512),
                                                  args, 0, stream);
        if (e != hipSuccess) {
            // 256 blocks at <=1 WG/CU occupancy co-reside on 256 CUs anyway.
            gru_persist<<<dim3(Bsz * NSL), dim3(512), 0, stream>>>(
                WtRp, WtCp, pre, h_buf, rh_buf, h_cnt, rh_cnt,
                out, hlast, t0, Tc);
        }
    }
}